// Round 1
// 319.766 us; speedup vs baseline: 1.0044x; 1.0044x over previous
//
#include <hip/hip_runtime.h>
#include <hip/hip_bf16.h>

// NLBlockND (embedded non-local block), MI355X/gfx950.
// Round 7: LDS XOR-swizzle (T2). Round-6 flash was LDS-bandwidth-bound:
// [kf][64][32] chunked K/V (64-B row stride) gave 4-way phase conflicts on
// every ds_read_b128 B-operand (SQ_LDS_BANK_CONFLICT 1.73e7, ~18% of cycles,
// plus serialization). New K [64][256] / V [256][64] linear rows, 16B-slot
// XOR-swizzled by row&7; global_load_lds keeps a linear LDS dest and the
// swizzle is applied on the per-lane GLOBAL source address (m173 pattern),
// reads use the same XOR (involution). Same fix (row&3) in gemm_nt.
// Shapes: N=4, C=512, CI=256, L=4096.

#define NB    4
#define CDIM  512
#define CIDIM 256
#define LDIM  4096
#define BN_EPS 1e-5f

typedef unsigned short u16;
typedef __attribute__((ext_vector_type(8))) short short8;  // 8 bf16 (4 VGPRs)
typedef __attribute__((ext_vector_type(4))) float f32x4;   // MFMA C/D
typedef __attribute__((ext_vector_type(4))) unsigned short u16x4;

// Workspace (float offsets). WY region hosts, in sequence: xT (bf16, dies
// after projections) -> OP partials (fp32, dies after merge) -> WY (fp32).
#define WY_OFF    0                  // 8,388,608 floats
#define THPH_OFF  8388608            // 4,194,304 floats (N,L,512 bf16 [theta|phi])
#define G_OFF     12582912           // 2,097,152 floats (g bf16, (N,CI,L))
#define Y_OFF     14680064           // 2,097,152 floats (yT bf16, (N,L,CI))
#define WTS_OFF   16777216           //   262,144 floats = 524,288 bf16 weights
#define BIAS2_OFF 17039360           //       512 floats ([tb|pb])
#define ML_OFF    17039872           //    65,536 floats (2 halves x N*L x {m,l})
#define ST_OFF    17105408           //     1,024 floats
// total 17,106,432 floats = 68.4 MB

__device__ __forceinline__ u16 f2b(float f) {  // fp32 -> bf16 RNE
    union { float f; unsigned u; } v; v.f = f;
    return (u16)((v.u + 0x7FFFu + ((v.u >> 16) & 1u)) >> 16);
}

__device__ __forceinline__ void gl_lds16(const u16* g, u16* l) {
    __builtin_amdgcn_global_load_lds(
        (const __attribute__((address_space(1))) void*)g,
        (__attribute__((address_space(3))) void*)l, 16, 0, 0);
}

// ---------------------------------------------------------------------------
// x (N,C,L) fp32 -> xT (N,L,C) bf16.  32x32 LDS tiles.
// ---------------------------------------------------------------------------
__global__ void transpose_x(const float* __restrict__ x, u16* __restrict__ xt) {
    __shared__ float tile[32][33];
    int n = blockIdx.z;
    int l0 = blockIdx.x * 32, c0 = blockIdx.y * 32;
    const float* xn = x + (size_t)n * CDIM * LDIM;
    u16* xtn = xt + (size_t)n * LDIM * CDIM;
    int tx = threadIdx.x, ty = threadIdx.y;  // (32, 8)
#pragma unroll
    for (int k = 0; k < 4; k++)
        tile[ty + 8 * k][tx] = xn[(size_t)(c0 + ty + 8 * k) * LDIM + l0 + tx];
    __syncthreads();
#pragma unroll
    for (int k = 0; k < 4; k++)
        xtn[(size_t)(l0 + ty + 8 * k) * CDIM + c0 + tx] = f2b(tile[tx][ty + 8 * k]);
}

// ---------------------------------------------------------------------------
// Cast the 4 weight matrices (each 131072 fp32) to bf16, concatenated.
// ---------------------------------------------------------------------------
__global__ void cast_w(const float* __restrict__ gw, const float* __restrict__ tw,
                       const float* __restrict__ pw, const float* __restrict__ zw,
                       u16* __restrict__ out) {
    int idx = blockIdx.x * 256 + threadIdx.x;
    if (idx >= 4 * 131072) return;
    int seg = idx >> 17, off = idx & 131071;
    const float* s = (seg == 0) ? gw : (seg == 1) ? tw : (seg == 2) ? pw : zw;
    out[idx] = f2b(s[off]);
}

__global__ void concat_bias(const float* __restrict__ tb, const float* __restrict__ pb,
                            float* __restrict__ out) {
    int i = blockIdx.x * 256 + threadIdx.x;
    if (i < 256) out[i] = tb[i];
    else if (i < 512) out[i] = pb[i - 256];
}

// ---------------------------------------------------------------------------
// NT-GEMM: D[m][n] = sum_k A[m][k]*B[n][k] (+bias). 128x128 tile, BK=32,
// 256 threads (4 waves 2x2), 16x16x32 bf16 MFMA, global_load_lds staging.
// Rows are 64 B (4 x 16B slots); slot index XOR-swizzled by row&3 so the
// ds_read_b128 phases are 2-way (free) instead of 4-way conflicted.
// ---------------------------------------------------------------------------
template <int BIAS_MODE, bool OUT_BF16>
__global__ __launch_bounds__(256)
void gemm_nt(const u16* __restrict__ A, const u16* __restrict__ B,
             void* __restrict__ Dv, const float* __restrict__ bias,
             int K, int lda, int ldb, int ldd,
             long batchA, long batchB, long batchD) {
    __shared__ __align__(16) u16 As[128 * 32];
    __shared__ __align__(16) u16 Bs[128 * 32];
    int z = blockIdx.z;
    A += (size_t)z * batchA;
    B += (size_t)z * batchB;

    int tid = threadIdx.x, lane = tid & 63, wave = tid >> 6;
    int n0 = blockIdx.x * 128, m0 = blockIdx.y * 128;
    int wr = wave >> 1, wc = wave & 1;

    f32x4 acc[4][4];
#pragma unroll
    for (int i = 0; i < 4; i++)
#pragma unroll
        for (int j = 0; j < 4; j++) acc[i][j] = (f32x4){0.f, 0.f, 0.f, 0.f};

    // staging: lane writes LDS row (wave*16 + lane>>2), phys slot lane&3;
    // fetch from swizzled source slot (lane&3) ^ (row&3).
    int sr = wave * 16 + (lane >> 2);
    int ss = ((lane & 3) ^ ((lane >> 2) & 3)) * 8;
    const u16* Ag0 = A + (size_t)(m0 + sr) * lda + ss;
    const u16* Ag1 = A + (size_t)(m0 + 64 + sr) * lda + ss;
    const u16* Bg0 = B + (size_t)(n0 + sr) * ldb + ss;
    const u16* Bg1 = B + (size_t)(n0 + 64 + sr) * ldb + ss;
    u16* Al0 = &As[(wave * 16) * 32];
    u16* Al1 = &As[(64 + wave * 16) * 32];
    u16* Bl0 = &Bs[(wave * 16) * 32];
    u16* Bl1 = &Bs[(64 + wave * 16) * 32];

    // read: row = w?*64 + (lane&15), slot = (lane>>4) ^ (row&3)
    int koff = ((lane >> 4) ^ (lane & 3)) * 8;
    int ra = (wr * 64 + (lane & 15)) * 32 + koff;
    int rb = (wc * 64 + (lane & 15)) * 32 + koff;

    for (int k0 = 0; k0 < K; k0 += 32) {
        __syncthreads();
        gl_lds16(Ag0 + k0, Al0);
        gl_lds16(Ag1 + k0, Al1);
        gl_lds16(Bg0 + k0, Bl0);
        gl_lds16(Bg1 + k0, Bl1);
        __syncthreads();

        short8 af[4], bf[4];
#pragma unroll
        for (int mt = 0; mt < 4; mt++) af[mt] = *(const short8*)&As[ra + mt * 16 * 32];
#pragma unroll
        for (int nt = 0; nt < 4; nt++) bf[nt] = *(const short8*)&Bs[rb + nt * 16 * 32];
#pragma unroll
        for (int mt = 0; mt < 4; mt++)
#pragma unroll
            for (int nt = 0; nt < 4; nt++)
                acc[mt][nt] = __builtin_amdgcn_mfma_f32_16x16x32_bf16(
                    af[mt], bf[nt], acc[mt][nt], 0, 0, 0);
    }

#pragma unroll
    for (int mt = 0; mt < 4; mt++) {
        int mg = m0 + wr * 64 + mt * 16 + (lane >> 4) * 4;
#pragma unroll
        for (int nt = 0; nt < 4; nt++) {
            int ng = n0 + wc * 64 + nt * 16 + (lane & 15);
#pragma unroll
            for (int r = 0; r < 4; r++) {
                float v = acc[mt][nt][r];
                if (BIAS_MODE == 1) v += bias[mg + r];
                if (BIAS_MODE == 2) v += bias[ng];
                if (OUT_BF16) {
                    u16* D = (u16*)Dv + (size_t)z * batchD;
                    D[(size_t)(mg + r) * ldd + ng] = f2b(v);
                } else {
                    float* D = (float*)Dv + (size_t)z * batchD;
                    D[(size_t)(mg + r) * ldd + ng] = v;
                }
            }
        }
    }
}

// ---------------------------------------------------------------------------
// Flash attention v2 (j-split), XOR-swizzled LDS.
// Block = one 64-row Q-tile x one half of the K/V column range. 256 threads
// = 4 waves, wave w owns Q rows [w*16, w*16+16). Q-frags in registers.
// K tile: Ks[64 j][256 ci] bf16 (512-B rows, 32 x 16B slots), slot ^= row&7.
// V tile: Vs[256 ci][64 j] bf16 (128-B rows,  8 x 16B slots), slot ^= row&7.
// Staged via global_load_lds with linear LDS dest + swizzled global source;
// ds_read_b128 uses the same XOR -> every 8-lane phase hits 8 distinct
// 16B slot groups (conflict-free; was 4-way).
// Emits unnormalized partial O (fp32) + per-row (m, l); merge_y combines.
// grid: 512 blocks; b&3 = batch (fixed per XCD for K/V L2 locality).
// ---------------------------------------------------------------------------
__global__ __launch_bounds__(256)
void flash_attn(const u16* __restrict__ THPH, const u16* __restrict__ G,
                float* __restrict__ OP, float* __restrict__ ML) {
    __shared__ __align__(16) u16 Ks[64 * 256];   // 32 KB
    __shared__ __align__(16) u16 Vs[256 * 64];   // 32 KB
    __shared__ __align__(16) u16 Ps[4][16][72];  // 9 KB (stride 144 B: phase-clean)

    int b = blockIdx.x;
    int n = b & 3;                 // XCD b%8 -> batches n, n+4 both = n mod 4
    int m = b >> 2;                // 0..127
    int qt = m >> 1;               // 64 Q-tiles
    int jh = m & 1;                // K/V half
    int q0 = qt * 64;

    const u16* TH = THPH + (size_t)n * LDIM * 512;
    const u16* PH = TH + 256;
    const u16* Gn = G + (size_t)n * LDIM * CIDIM;
    float* OPh = OP + ((size_t)jh * NB + n) * LDIM * CIDIM;
    float* MLh = ML + ((size_t)jh * NB + n) * LDIM * 2;

    int tid = threadIdx.x, lane = tid & 63, wave = tid >> 6;
    int quad = lane >> 4, lan = lane & 15;

    // ---- Q fragments, loop-invariant, straight from global ----
    short8 qf[8];
    {
        const u16* qb = TH + (size_t)(q0 + wave * 16 + lan) * 512 + quad * 8;
#pragma unroll
        for (int kf = 0; kf < 8; kf++) qf[kf] = *(const short8*)(qb + kf * 32);
    }

    // staging decompositions (per-issue row / swizzled slot)
    int krow0 = wave * 16 + (lane >> 5);           // + 2*i ; phys slot = lane&31
    int vrow0 = wave * 64 + (lane >> 3);           // + 8*i ; phys slot = lane&7
    int vslot = ((lane & 7) ^ ((lane >> 3) & 7)) * 8;  // r&7 = (lane>>3)&7, i-invariant

    f32x4 o[16];
#pragma unroll
    for (int i = 0; i < 16; i++) o[i] = (f32x4){0.f, 0.f, 0.f, 0.f};
    float mrow[4] = {-1e30f, -1e30f, -1e30f, -1e30f};
    float lrow[4] = {0.f, 0.f, 0.f, 0.f};

#pragma unroll 1
    for (int jt = 0; jt < 32; jt++) {
        int j0 = (jh * 32 + jt) * 64;
        __syncthreads();
        // stage K tile: 64 rows x 512 B; wave fills 16 rows, 2 rows per issue
#pragma unroll
        for (int i = 0; i < 8; i++) {
            int r = krow0 + 2 * i;
            int s = ((lane & 31) ^ (r & 7)) * 8;
            gl_lds16(PH + (size_t)(j0 + r) * 512 + s,
                     &Ks[(wave * 16 + 2 * i) * 256]);
        }
        // stage V tile: 256 rows x 128 B; wave fills 64 rows, 8 rows per issue
#pragma unroll
        for (int i = 0; i < 8; i++) {
            int r = vrow0 + 8 * i;
            gl_lds16(Gn + (size_t)r * LDIM + j0 + vslot,
                     &Vs[(wave * 64 + 8 * i) * 64]);
        }
        __syncthreads();

        // ---- S = Q K^T (16 rows x 64 cols per wave) ----
        f32x4 s[4];
#pragma unroll
        for (int ct = 0; ct < 4; ct++) s[ct] = (f32x4){0.f, 0.f, 0.f, 0.f};
#pragma unroll
        for (int kf = 0; kf < 8; kf++)
#pragma unroll
            for (int ct = 0; ct < 4; ct++) {
                int row = ct * 16 + lan;
                short8 bb = *(const short8*)&Ks[row * 256 +
                                (((kf * 4 + quad) ^ (lan & 7)) << 3)];
                s[ct] = __builtin_amdgcn_mfma_f32_16x16x32_bf16(qf[kf], bb, s[ct], 0, 0, 0);
            }

        // ---- online softmax ----
        float alpha[4];
#pragma unroll
        for (int r = 0; r < 4; r++) {
            float mx = fmaxf(fmaxf(s[0][r], s[1][r]), fmaxf(s[2][r], s[3][r]));
#pragma unroll
            for (int msk = 1; msk <= 8; msk <<= 1)
                mx = fmaxf(mx, __shfl_xor(mx, msk, 64));
            float mnew = fmaxf(mrow[r], mx);
            alpha[r] = __expf(mrow[r] - mnew);
            float rs = 0.f;
#pragma unroll
            for (int ct = 0; ct < 4; ct++) {
                float p = __expf(s[ct][r] - mnew);
                rs += p;
                Ps[wave][quad * 4 + r][ct * 16 + lan] = f2b(p);
            }
#pragma unroll
            for (int msk = 1; msk <= 8; msk <<= 1)
                rs += __shfl_xor(rs, msk, 64);
            lrow[r] = lrow[r] * alpha[r] + rs;
            mrow[r] = mnew;
        }
#pragma unroll
        for (int ot = 0; ot < 16; ot++)
#pragma unroll
            for (int r = 0; r < 4; r++) o[ot][r] *= alpha[r];

        // ---- O += P V^T (P wave-private; in-wave lgkm ordering) ----
#pragma unroll
        for (int kf2 = 0; kf2 < 2; kf2++) {
            short8 a = *(const short8*)&Ps[wave][lan][kf2 * 32 + quad * 8];
#pragma unroll
            for (int ot = 0; ot < 16; ot++) {
                int row = ot * 16 + lan;
                short8 bb = *(const short8*)&Vs[row * 64 +
                                (((kf2 * 4 + quad) ^ (lan & 7)) << 3)];
                o[ot] = __builtin_amdgcn_mfma_f32_16x16x32_bf16(a, bb, o[ot], 0, 0, 0);
            }
        }
    }

    // ---- epilogue: unnormalized partial O + (m, l) per row ----
#pragma unroll
    for (int r = 0; r < 4; r++) {
        int row = q0 + wave * 16 + quad * 4 + r;
        if (lan == 0) {
            MLh[row * 2] = mrow[r];
            MLh[row * 2 + 1] = lrow[r];
        }
#pragma unroll
        for (int ot = 0; ot < 16; ot++)
            OPh[(size_t)row * CIDIM + ot * 16 + lan] = o[ot][r];
    }
}

// ---------------------------------------------------------------------------
// Merge the two j-halves: Y = (Oa*e^(ma-M) + Ob*e^(mb-M)) / (la*e^.. + lb*e^..)
// ---------------------------------------------------------------------------
__global__ void merge_y(const float* __restrict__ OP, const float* __restrict__ ML,
                        u16* __restrict__ Y) {
    const size_t HALF = (size_t)NB * LDIM * CIDIM;
    const int HALF_ML = NB * LDIM * 2;
    int i4 = blockIdx.x * 256 + threadIdx.x;     // over N*L*CI/4
    int row = i4 >> 6;                           // n*L + l
    float ma = ML[row * 2], la = ML[row * 2 + 1];
    float mb = ML[HALF_ML + row * 2], lb = ML[HALF_ML + row * 2 + 1];
    float M = fmaxf(ma, mb);
    float ea = __expf(ma - M), eb = __expf(mb - M);
    float inv = 1.f / (la * ea + lb * eb);
    float4 oa = ((const float4*)OP)[i4];
    float4 ob = ((const float4*)(OP + HALF))[i4];
    u16x4 y;
    y.x = f2b((oa.x * ea + ob.x * eb) * inv);
    y.y = f2b((oa.y * ea + ob.y * eb) * inv);
    y.z = f2b((oa.z * ea + ob.z * eb) * inv);
    y.w = f2b((oa.w * ea + ob.w * eb) * inv);
    ((u16x4*)Y)[i4] = y;
}

// ---------------------------------------------------------------------------
// BN stats per channel o over (N, L). WY layout (N, C, L) fp32.
// ---------------------------------------------------------------------------
__global__ void bn_stats_kernel(const float* __restrict__ WY, float* __restrict__ stats) {
    int o = blockIdx.x, tid = threadIdx.x, lane = tid & 63, wave = tid >> 6;
    float s = 0.f, s2 = 0.f;
    for (int n = 0; n < NB; n++) {
        const float4* p = (const float4*)(WY + (size_t)(n * CDIM + o) * LDIM);
        for (int i = tid; i < LDIM / 4; i += 256) {
            float4 v = p[i];
            s += v.x + v.y + v.z + v.w;
            s2 += v.x * v.x + v.y * v.y + v.z * v.z + v.w * v.w;
        }
    }
    for (int o2 = 32; o2 > 0; o2 >>= 1) {
        s += __shfl_xor(s, o2, 64);
        s2 += __shfl_xor(s2, o2, 64);
    }
    __shared__ float rs[4], rs2[4];
    if (lane == 0) { rs[wave] = s; rs2[wave] = s2; }
    __syncthreads();
    if (tid == 0) {
        float S = rs[0] + rs[1] + rs[2] + rs[3];
        float S2 = rs2[0] + rs2[1] + rs2[2] + rs2[3];
        const float cnt = (float)(NB * LDIM);
        float mean = S / cnt;
        float var = S2 / cnt - mean * mean;
        stats[o] = mean;
        stats[CDIM + o] = rsqrtf(var + BN_EPS);
    }
}

// ---------------------------------------------------------------------------
// BN apply + residual, float4 vectorized.
// ---------------------------------------------------------------------------
__global__ void bn_apply_kernel(const float* __restrict__ WY, const float* __restrict__ stats,
                                const float* __restrict__ x,
                                const float* __restrict__ gamma, const float* __restrict__ beta,
                                float* __restrict__ out) {
    int i4 = blockIdx.x * 256 + threadIdx.x;  // < N*C*L/4
    int o = (i4 >> 10) & (CDIM - 1);
    float m = stats[o], is = stats[CDIM + o];
    float ga = gamma[o], be = beta[o];
    float4 w = ((const float4*)WY)[i4];
    float4 xv = ((const float4*)x)[i4];
    float4 r;
    r.x = (w.x - m) * is * ga + be + xv.x;
    r.y = (w.y - m) * is * ga + be + xv.y;
    r.z = (w.z - m) * is * ga + be + xv.z;
    r.w = (w.w - m) * is * ga + be + xv.w;
    ((float4*)out)[i4] = r;
}

// ---------------------------------------------------------------------------
extern "C" void kernel_launch(void* const* d_in, const int* in_sizes, int n_in,
                              void* d_out, int out_size, void* d_ws, size_t ws_size,
                              hipStream_t stream) {
    const float* x   = (const float*)d_in[0];
    const float* gw  = (const float*)d_in[1];
    const float* gb  = (const float*)d_in[2];
    const float* tw  = (const float*)d_in[3];
    const float* tb  = (const float*)d_in[4];
    const float* pw  = (const float*)d_in[5];
    const float* pb  = (const float*)d_in[6];
    const float* zw  = (const float*)d_in[7];
    const float* zb  = (const float*)d_in[8];
    const float* bng = (const float*)d_in[9];
    const float* bnb = (const float*)d_in[10];
    float* out = (float*)d_out;
    float* ws  = (float*)d_ws;

    float* WY   = ws + WY_OFF;
    u16*   xT   = (u16*)(ws + WY_OFF);      // dies before flash writes OP
    float* OP   = ws + WY_OFF;              // partials; die before wz writes WY
    u16*   THPH = (u16*)(ws + THPH_OFF);    // (N, L, 512) = [theta | phi]
    u16*   G    = (u16*)(ws + G_OFF);       // (N, CI, L)
    u16*   Y    = (u16*)(ws + Y_OFF);       // (N, L, CI)
    u16*   WB   = (u16*)(ws + WTS_OFF);     // [gw | tw | pw | zw] bf16
    float* BC   = ws + BIAS2_OFF;           // [tb | pb]
    float* ML   = ws + ML_OFF;
    float* ST   = ws + ST_OFF;

    const long LC   = (long)LDIM * CDIM;    // xT batch (u16)
    const long LCI  = (long)LDIM * CIDIM;
    const long L512 = (long)LDIM * 512;     // THPH batch (u16)
    const long CL   = (long)CDIM * LDIM;    // WY batch (fp32)

    transpose_x<<<dim3(LDIM / 32, CDIM / 32, NB), dim3(32, 8), 0, stream>>>(x, xT);
    cast_w<<<2048, 256, 0, stream>>>(gw, tw, pw, zw, WB);
    concat_bias<<<2, 256, 0, stream>>>(tb, pb, BC);

    // THPH (N,L,512) = xT(L,C) x [tw;pw](512,C)^T   [bias per-n = BC]
    gemm_nt<2, true><<<dim3(4, 32, NB), 256, 0, stream>>>(
        xT, WB + 131072, THPH, BC, CDIM, CDIM, CDIM, 512, LC, 0, L512);
    // g (N,CI,L) = gw(CI,C) x xT(L,C)^T             [bias per-m]
    gemm_nt<1, true><<<dim3(32, 2, NB), 256, 0, stream>>>(
        WB, xT, G, gb, CDIM, CDIM, CDIM, LDIM, 0, LC, LCI);

    // fused attention (j-split x2) + merge
    flash_attn<<<dim3(512), 256, 0, stream>>>(THPH, G, OP, ML);
    merge_y<<<dim3(NB * LDIM * CIDIM / 4 / 256), 256, 0, stream>>>(OP, ML, Y);

    // WY (N,C,L) fp32 = zw(C,CI) x yT(L,CI)^T  [bias per-m]
    gemm_nt<1, false><<<dim3(32, 4, NB), 256, 0, stream>>>(
        WB + 393216, Y, (void*)WY, zb, CIDIM, CIDIM, CIDIM, LDIM, 0, LCI, CL);

    bn_stats_kernel<<<dim3(CDIM), 256, 0, stream>>>(WY, ST);
    bn_apply_kernel<<<dim3(NB * CDIM * LDIM / 4 / 256), 256, 0, stream>>>(
        WY, ST, x, bng, bnb, out);
}